// Round 3
// baseline (268.510 us; speedup 1.0000x reference)
//
#include <hip/hip_runtime.h>
#include <math.h>

namespace {
constexpr int Bn = 4, Rn = 16384, Sn = 128;
constexpr int NRAY = Bn * Rn;          // 65536 rays
constexpr int SI   = Sn - 1;           // 127 intervals
constexpr int NG   = NRAY / 4;         // 16384 groups of 4 rays (one block-iter each)
constexpr int GRID = 2048;             // 8 blocks/CU, all co-resident; 8 iters/block
// Output layout: tuple concatenated flat in return order
constexpr size_t OFF_RGB   = 0;                                  // [B,R,3]
constexpr size_t OFF_DEPTH = OFF_RGB   + (size_t)NRAY * 3;       // [B,R,1]
constexpr size_t OFF_W     = OFF_DEPTH + (size_t)NRAY;           // [B,R,SI,1]
constexpr size_t OFF_WALL  = OFF_W     + (size_t)NRAY * SI;      // [B,R,SI,1]
constexpr size_t OFF_ALPHA = OFF_WALL  + (size_t)NRAY * SI;      // [B,R,SI,1]
constexpr size_t OFF_DMID  = OFF_ALPHA + (size_t)NRAY * SI;      // [B,R,SI,1]
constexpr float  EPSF  = 1e-10f;
constexpr float  LOG2E = 1.44269504088896340736f;
typedef float f4 __attribute__((ext_vector_type(4)));
}

// DPP move helper: returns src shifted per ctrl; invalid/masked lanes get `oldv`.
template <int ctrl, int rmask>
__device__ __forceinline__ float dpp_mov(float x, float oldv) {
    return __int_as_float(__builtin_amdgcn_update_dpp(
        __float_as_int(oldv), __float_as_int(x), ctrl, rmask, 0xf, false));
}

// Wave64 inclusive prefix PRODUCT via DPP.
__device__ __forceinline__ float scan_mul(float x) {
    x *= dpp_mov<0x111, 0xf>(x, 1.0f);  // row_shr:1
    x *= dpp_mov<0x112, 0xf>(x, 1.0f);  // row_shr:2
    x *= dpp_mov<0x114, 0xf>(x, 1.0f);  // row_shr:4
    x *= dpp_mov<0x118, 0xf>(x, 1.0f);  // row_shr:8
    x *= dpp_mov<0x142, 0xa>(x, 1.0f);  // row_bcast:15 -> rows 1,3
    x *= dpp_mov<0x143, 0xc>(x, 1.0f);  // row_bcast:31 -> rows 2,3
    return x;
}

// Wave64 inclusive prefix SUM via DPP; lane 63 holds the wave total.
__device__ __forceinline__ float scan_add(float x) {
    x += dpp_mov<0x111, 0xf>(x, 0.0f);
    x += dpp_mov<0x112, 0xf>(x, 0.0f);
    x += dpp_mov<0x114, 0xf>(x, 0.0f);
    x += dpp_mov<0x118, 0xf>(x, 0.0f);
    x += dpp_mov<0x142, 0xa>(x, 0.0f);
    x += dpp_mov<0x143, 0xc>(x, 0.0f);
    return x;
}

// lane i gets lane i+1's value (wave_shl:1); lane 63 gets 0.
__device__ __forceinline__ float next_lane(float x) {
    return dpp_mov<0x130, 0xf>(x, 0.0f);
}

__device__ __forceinline__ void load_ray(
    const float* __restrict__ colors, const float* __restrict__ dlog,
    const float* __restrict__ depths, int ray, int lane,
    float2& d, float2& g, float2& c0, float2& c1, float2& c2)
{
    const float2* dp = reinterpret_cast<const float2*>(depths) + (size_t)ray * (Sn / 2);
    const float2* gp = reinterpret_cast<const float2*>(dlog)   + (size_t)ray * (Sn / 2);
    const float2* cp = reinterpret_cast<const float2*>(colors) + (size_t)ray * (Sn * 3 / 2);
    d  = dp[lane];
    g  = gp[lane];
    c0 = cp[lane * 3 + 0];
    c1 = cp[lane * 3 + 1];
    c2 = cp[lane * 3 + 2];
}

// 2048 persistent blocks; each iteration a block processes 4 rays (1 ray/wave),
// stages per-interval outputs compactly in LDS, then writes them as fully
// packed 16B-aligned nontemporal dwordx4 stores (a 4-ray group = 508 dwords =
// exactly 127 float4s per array).
__global__ __launch_bounds__(256, 8) void raymarch_kernel(
    const float* __restrict__ colors,
    const float* __restrict__ dlog,
    const float* __restrict__ depths,
    float* __restrict__ out)
{
    __shared__ __attribute__((aligned(16))) float st[3 * 508];  // w | alpha | dmid

    const int tid  = threadIdx.x;
    const int wv   = tid >> 6;     // ray slot within the 4-ray group
    const int lane = tid & 63;

    int g = blockIdx.x;
    float2 d, dg, c0, c1, c2;
    load_ray(colors, dlog, depths, 4 * g + wv, lane, d, dg, c0, c1, c2);

    while (true) {
        const int gn = g + GRID;
        const bool has_next = (gn < NG);
        float2 d_n, dg_n, c0_n, c1_n, c2_n;
        if (has_next)   // prefetch next group's inputs (hidden behind this iter)
            load_ray(colors, dlog, depths, 4 * gn + wv, lane, d_n, dg_n, c0_n, c1_n, c2_n);

        // ---- phase A: per-wave compute for ray 4g+wv ----
        float d2  = next_lane(d.x);
        float g2  = next_lane(dg.x);
        float cnx = next_lane(c0.x);
        float cny = next_lane(c0.y);
        float cnz = next_lane(c1.x);

        const bool valid1 = (lane < 63);   // interval 2*63+1 = 127 does not exist

        float delta0 = d.y - d.x;
        float dm0    = 0.5f * (d.x + d.y);
        float x0     = 0.5f * (dg.x + dg.y) - 1.0f;
        float cm0x   = 0.5f * (c0.x + c1.y);
        float cm0y   = 0.5f * (c0.y + c2.x);
        float cm0z   = 0.5f * (c1.x + c2.y);

        float delta1 = valid1 ? (d2 - d.y)                   : 0.0f;
        float dm1    = valid1 ? 0.5f * (d.y + d2)            : 0.0f;
        float x1     = valid1 ? (0.5f * (dg.y + g2) - 1.0f)  : 0.0f;
        float cm1x   = valid1 ? 0.5f * (c1.y + cnx)          : 0.0f;
        float cm1y   = valid1 ? 0.5f * (c2.x + cny)          : 0.0f;
        float cm1z   = valid1 ? 0.5f * (c2.y + cnz)          : 0.0f;

        // softplus+alpha in base-2 HW transcendentals:
        //   l = log2(1+exp2(x*log2e)) = softplus(x)/ln2; alpha = 1-exp2(-l*delta)
        float l0 = __log2f(1.0f + exp2f(x0 * LOG2E));
        float l1 = __log2f(1.0f + exp2f(x1 * LOG2E));
        float alpha0 = 1.0f - exp2f(-l0 * delta0);
        float alpha1 = 1.0f - exp2f(-l1 * delta1);      // 0 for lane 63
        float t0 = 1.0f - alpha0 + EPSF;
        float t1 = valid1 ? (1.0f - alpha1 + EPSF) : 1.0f;

        float s  = scan_mul(t0 * t1);
        float T0 = dpp_mov<0x138, 0xf>(s, 1.0f);        // wave_shr:1; lane0 -> 1
        float T1 = T0 * t0;

        float w0 = (alpha0 + EPSF) * T0;
        float w1 = valid1 ? (alpha1 + EPSF) * T1 : 0.0f;

        // stage compactly: ray wv occupies [wv*127, wv*127+127) in each region
        const int c = wv * SI + 2 * lane;
        st[c]            = w0;
        st[508 + c]      = alpha0;
        st[1016 + c]     = dm0;
        if (valid1) {               // lane 63's slot c+1 belongs to ray wv+1
            st[c + 1]        = w1;
            st[508 + c + 1]  = alpha1;
            st[1016 + c + 1] = dm1;
        }

        // composites: sum-scans, totals in lane 63
        float wsum = scan_add(w0 + w1);
        float rx   = scan_add(w0 * cm0x + w1 * cm1x);
        float ry   = scan_add(w0 * cm0y + w1 * cm1y);
        float rz   = scan_add(w0 * cm0z + w1 * cm1z);
        float dsum = scan_add(w0 * dm0 + w1 * dm1);

        if (lane == 63) {
            const int ray = 4 * g + wv;
            float cd = dsum / (EPSF + wsum);
            if (isnan(cd)) cd = 100.0f;
            cd = fminf(fmaxf(cd, 0.1f), 100.0f);
            out[OFF_RGB + (size_t)ray * 3 + 0] = rx * 2.0f - 1.0f;
            out[OFF_RGB + (size_t)ray * 3 + 1] = ry * 2.0f - 1.0f;
            out[OFF_RGB + (size_t)ray * 3 + 2] = rz * 2.0f - 1.0f;
            out[OFF_DEPTH + ray] = cd;
        }

        __syncthreads();

        // ---- phase B: packed dwordx4 NT stores of the 4 staged arrays ----
        {
            constexpr size_t arrOFF[4] = { OFF_W, OFF_WALL, OFF_ALPHA, OFF_DMID };
            const size_t blockbase = (size_t)508 * g;   // dword offset into each array
            #pragma unroll
            for (int pass = 0; pass < 2; ++pass) {
                const int q = tid + 256 * pass;     // 0..511
                const int a = q >> 7;               // target array 0..3
                const int j = q & 127;              // float4 index within block-span
                if (j < 127) {
                    const int srcreg = (a < 2) ? 0 : (a - 1);   // W,WALL share region 0
                    f4 v = *reinterpret_cast<const f4*>(st + srcreg * 508 + 4 * j);
                    __builtin_nontemporal_store(
                        v, reinterpret_cast<f4*>(out + arrOFF[a] + blockbase + 4 * j));
                }
            }
        }

        __syncthreads();   // LDS safe to overwrite next iteration

        if (!has_next) break;
        g = gn;
        d = d_n; dg = dg_n; c0 = c0_n; c1 = c1_n; c2 = c2_n;
    }
}

extern "C" void kernel_launch(void* const* d_in, const int* in_sizes, int n_in,
                              void* d_out, int out_size, void* d_ws, size_t ws_size,
                              hipStream_t stream) {
    const float* colors = (const float*)d_in[0];
    const float* dlog   = (const float*)d_in[1];
    const float* depths = (const float*)d_in[2];
    float* out = (float*)d_out;

    hipLaunchKernelGGL(raymarch_kernel, dim3(GRID), dim3(256), 0, stream,
                       colors, dlog, depths, out);
}